// Round 11
// baseline (129.309 us; speedup 1.0000x reference)
//
#include <hip/hip_runtime.h>
#include <hip/hip_bf16.h>
#include <math.h>

#define NH 8
#define HD 32
#define SEQ 2048
#define DM 256
#define SCALE 0.17677669529663687f      // 1/sqrt(32)
#define INV_SCALE 5.656854249492381f    // sqrt(32)
#define LOG2E 1.4426950408889634f
#define QSC (SCALE * LOG2E)
#define MNEG (-1e9f * LOG2E)

typedef float f32x4 __attribute__((ext_vector_type(4)));
typedef __bf16 bf16x8 __attribute__((ext_vector_type(8)));

#define GLOAD(g, l) __builtin_amdgcn_global_load_lds( \
    (const __attribute__((address_space(1))) void*)(g), \
    (__attribute__((address_space(3))) void*)(l), 16, 0, 0)

// ============ prep: LDS-tiled W transposes, MT+flag, SUFn/PREn, WV2T, cb ============
__global__ void k_prep(const float* __restrict__ mask,
                       const float* __restrict__ Wq, const float* __restrict__ Wk,
                       const float* __restrict__ Wv, const float* __restrict__ Wo,
                       const float* __restrict__ bq, const float* __restrict__ tbl,
                       __bf16* __restrict__ Wt, __bf16* __restrict__ WoT,
                       float* __restrict__ MT,
                       __bf16* __restrict__ SUFn, __bf16* __restrict__ PREn,
                       float* __restrict__ WV2T, float* __restrict__ cb,
                       int* __restrict__ MFLAG) {
  const int blk = blockIdx.x, tid = threadIdx.x;
  __shared__ float ts[64][65];
  __shared__ int okl;
  if (blk < 64) {                        // LDS-tiled transposes (48 QKV + 16 Wo)
    const int idx = blk;
    const float* W;
    __bf16* dst;
    int tile;
    if (idx < 48) {
      int which = idx >> 4;
      W = which == 0 ? Wq : (which == 1 ? Wk : Wv);
      dst = Wt + which * 65536;
      tile = idx & 15;
    } else {
      W = Wo; dst = WoT; tile = idx - 48;
    }
    const int tr = (tile >> 2) * 64, tc = (tile & 3) * 64;
#pragma unroll
    for (int p = 0; p < 4; ++p) {
      int row = p * 16 + (tid >> 4);
      int col = (tid & 15) * 4;
      float4 v = *(const float4*)(W + (size_t)(tr + row) * 256 + tc + col);
      ts[row][col] = v.x; ts[row][col + 1] = v.y;
      ts[row][col + 2] = v.z; ts[row][col + 3] = v.w;
    }
    __syncthreads();
#pragma unroll
    for (int p = 0; p < 2; ++p) {
      int n = p * 32 + (tid >> 3);
      int kb = (tid & 7) * 8;
      union { __bf16 h[8]; bf16x8 v; } o;
#pragma unroll
      for (int e = 0; e < 8; ++e) o.h[e] = (__bf16)ts[kb + e][n];
      *(bf16x8*)(dst + (size_t)(tc + n) * 256 + tr + kb) = o.v;
    }
  } else if (blk == 64) {                // MT (log2e-folded) + mask-ones flag
    if (tid == 0) okl = 1;
    __syncthreads();
    bool ok = true;
    for (int i = tid; i < 4 * SEQ; i += 256) {
      float mv = mask[i];
      MT[i] = (1.0f - mv) * MNEG;
      ok &= (mv == 1.0f);
    }
    if (!ok) atomicAnd(&okl, 0);
    __syncthreads();
    if (tid == 0) MFLAG[0] = okl;
  } else if (blk == 65) {                // SUFn/PREn (negated prefix sums, /SCALE)
    for (int idx = tid; idx < 1024; idx += 256) {
      int j = idx >> 5, d = idx & 31;
      float s = 0.f;
      for (int u = j + 33; u <= 63; ++u) s += tbl[u * 32 + d];
      SUFn[idx] = (__bf16)(-s * INV_SCALE);
    }
    for (int idx = tid; idx < 1024; idx += 256) {
      int jj = idx >> 5, d = idx & 31;
      float s = 0.f;
      for (int u = 1; u <= jj; ++u) s += tbl[u * 32 + d];
      PREn[idx] = (__bf16)(-s * INV_SCALE);
    }
  } else if (blk < 82) {                 // WV2T[16][256] (x log2e)
    int tg = (blk - 66) * 256 + tid;
    int hv = tg >> 8, k = tg & 255;
    const float* T = tbl + ((hv & 1) ? 0 : 64 * 32);
    const float* w = Wq + (size_t)k * 256 + (hv >> 1) * 32;
    float acc = 0.f;
#pragma unroll
    for (int d = 0; d < 32; ++d) acc = fmaf(w[d], T[d], acc);
    WV2T[hv * 256 + k] = acc * LOG2E;
  } else {                               // cb[16]
    if (tid < 16) {
      const float* T = tbl + ((tid & 1) ? 0 : 64 * 32);
      float a = 0.f;
#pragma unroll
      for (int d = 0; d < 32; ++d) a = fmaf(bq[(tid >> 1) * 32 + d], T[d], a);
      cb[tid] = a * LOG2E;
    }
  }
}

// ============ REL = (X @ WV2T^T + cb) + fused X->bf16 conversion ============
__launch_bounds__(256)
__global__ void k_rel(const float* __restrict__ X, const float* __restrict__ WV2T,
                      const float* __restrict__ cb, float* __restrict__ REL,
                      __bf16* __restrict__ Xb) {
  __shared__ float Xs[32][260];
  __shared__ float Ws[16][260];
  const int tid = threadIdx.x;
  const size_t base = (size_t)blockIdx.x * 32 * 256;
#pragma unroll
  for (int p = 0; p < 8; ++p) {
    int idx = p * 1024 + tid * 4;
    float4 v = *(const float4*)(X + base + idx);
    *(float4*)&Xs[idx >> 8][idx & 255] = v;
  }
#pragma unroll
  for (int p = 0; p < 4; ++p) {
    int idx = p * 1024 + tid * 4;
    float4 v = *(const float4*)(WV2T + idx);
    *(float4*)&Ws[idx >> 8][idx & 255] = v;
  }
  __syncthreads();
  // fused bf16 conversion (reads LDS, writes Xb coalesced)
#pragma unroll
  for (int p = 0; p < 4; ++p) {
    int idx = p * 2048 + tid * 8;
    int row = idx >> 8, col = idx & 255;
    float4 a = *(const float4*)&Xs[row][col];
    float4 b4 = *(const float4*)&Xs[row][col + 4];
    union { __bf16 h[8]; bf16x8 v; } o;
    o.h[0] = (__bf16)a.x;  o.h[1] = (__bf16)a.y;
    o.h[2] = (__bf16)a.z;  o.h[3] = (__bf16)a.w;
    o.h[4] = (__bf16)b4.x; o.h[5] = (__bf16)b4.y;
    o.h[6] = (__bf16)b4.z; o.h[7] = (__bf16)b4.w;
    *(bf16x8*)(Xb + base + idx) = o.v;
  }
  const int hv = tid & 15, rl = tid >> 4;
  float a0 = cb[hv], a1 = a0;
  const float* xs0 = &Xs[rl][0];
  const float* xs1 = &Xs[rl + 16][0];
  const float* wsp = &Ws[hv][0];
#pragma unroll 8
  for (int k = 0; k < 256; ++k) {
    float w = wsp[k];
    a0 = fmaf(xs0[k], w, a0);
    a1 = fmaf(xs1[k], w, a1);
  }
  const int row0 = blockIdx.x * 32 + rl;
  const int h = hv >> 1, v = hv & 1;
  const int b0i = row0 >> 11, s0 = row0 & 2047;
  REL[((size_t)(b0i * NH + h) * SEQ + s0) * 2 + v] = a0;
  const int r1 = row0 + 16;
  const int b1i = r1 >> 11, s1 = r1 & 2047;
  REL[((size_t)(b1i * NH + h) * SEQ + s1) * 2 + v] = a1;
}

// ============ bf16 MFMA GEMM (r5/r10 proven config) ============
template <int MODE>
__launch_bounds__(256)
__global__ void k_gemm(const __bf16* __restrict__ A, const __bf16* __restrict__ Bt,
                       const float* __restrict__ b0, const float* __restrict__ b1,
                       const float* __restrict__ b2,
                       __bf16* __restrict__ Qb, __bf16* __restrict__ Kb,
                       __bf16* __restrict__ VTout, float* __restrict__ Y) {
  constexpr int BN = (MODE == 0) ? 128 : 64;
  constexpr int NFJ = BN / 32;
  __shared__ __align__(16) __bf16 As[128 * 64];
  __shared__ __align__(16) __bf16 Bs[BN * 64];
  const int tid = threadIdx.x, lane = tid & 63, wid = tid >> 6;
  const int l16 = lane & 15, lhi = lane >> 4;
  const int wr = wid >> 1, wc = wid & 1;
  const int m0 = blockIdx.x * 128, n0 = blockIdx.y * BN;

  f32x4 acc[4][NFJ];
#pragma unroll
  for (int i = 0; i < 4; ++i)
#pragma unroll
    for (int j = 0; j < NFJ; ++j) acc[i][j] = (f32x4){0.f, 0.f, 0.f, 0.f};

  for (int k0 = 0; k0 < 256; k0 += 64) {
    __syncthreads();
#pragma unroll
    for (int cc = 0; cc < 4; ++cc) {
      int cl = tid + cc * 256;
      int row = cl >> 3, kc = cl & 7;
      int k = k0 + ((kc ^ (row & 7)) * 8);
      const __bf16* src;
      if constexpr (MODE == 0) {
        src = A + (size_t)(m0 + row) * 256 + k;
      } else {
        int r = m0 + row, bb = r >> 11, s = r & 2047, h = k >> 5, dh = k & 31;
        src = A + ((size_t)(bb * NH + h) * SEQ + s) * HD + dh;
      }
      GLOAD(src, (__bf16*)As + (size_t)cl * 8);
    }
#pragma unroll
    for (int cc = 0; cc < NFJ; ++cc) {
      int cl = tid + cc * 256;
      int row = cl >> 3, kc = cl & 7;
      int k = k0 + ((kc ^ (row & 7)) * 8);
      GLOAD(Bt + (size_t)(n0 + row) * 256 + k, (__bf16*)Bs + (size_t)cl * 8);
    }
    __syncthreads();
#pragma unroll
    for (int kk = 0; kk < 64; kk += 32) {
      bf16x8 af[4], bfr[NFJ];
#pragma unroll
      for (int fi = 0; fi < 4; ++fi) {
        int row = wr * 64 + fi * 16 + l16;
        af[fi] = *(const bf16x8*)(As + row * 64 + ((((kk >> 3) + lhi) ^ (row & 7)) * 8));
      }
#pragma unroll
      for (int fj = 0; fj < NFJ; ++fj) {
        int row = wc * (BN / 2) + fj * 16 + l16;
        bfr[fj] = *(const bf16x8*)(Bs + row * 64 + ((((kk >> 3) + lhi) ^ (row & 7)) * 8));
      }
#pragma unroll
      for (int fi = 0; fi < 4; ++fi)
#pragma unroll
        for (int fj = 0; fj < NFJ; ++fj)
          acc[fi][fj] = __builtin_amdgcn_mfma_f32_16x16x32_bf16(af[fi], bfr[fj], acc[fi][fj], 0, 0, 0);
    }
  }
#pragma unroll
  for (int fi = 0; fi < 4; ++fi) {
#pragma unroll
    for (int fj = 0; fj < NFJ; ++fj) {
      int mrow = m0 + wr * 64 + fi * 16 + lhi * 4;
      int ncol = n0 + wc * (BN / 2) + fj * 16 + l16;
      if constexpr (MODE == 0) {
        int which = ncol >> 8, nw = ncol & 255, h = nw >> 5, dh = nw & 31;
        int bb = mrow >> 11, s0 = mrow & 2047;
        if (which == 2) {
          union { __bf16 h4[4]; uint2 u; } o;
#pragma unroll
          for (int r = 0; r < 4; ++r) o.h4[r] = (__bf16)(acc[fi][fj][r] + b2[nw]);
          *(uint2*)(VTout + ((size_t)(bb * NH + h) * HD + dh) * SEQ + s0) = o.u;
        } else {
          const float* bias = which == 0 ? b0 : b1;
#pragma unroll
          for (int r = 0; r < 4; ++r) {
            float v = acc[fi][fj][r] + bias[nw];
            size_t oi = ((size_t)(bb * NH + h) * SEQ + (s0 + r)) * HD + dh;
            if (which == 0) Qb[oi] = (__bf16)(v * QSC);
            else Kb[oi] = (__bf16)v;
          }
        }
      } else {
#pragma unroll
        for (int r = 0; r < 4; ++r)
          Y[(size_t)(mrow + r) * 256 + ncol] = acc[fi][fj][r] + b0[ncol];
      }
    }
  }
}

// ============ flash: K direct from global into registers (one-tile prefetch),
//              V in dbuf LDS, static-C0, XCD swizzle, 2-phase P-LDS, ones-MFMA lsum ============
__launch_bounds__(512, 4)
__global__ void k_flash(const __bf16* __restrict__ Qb, const __bf16* __restrict__ Kb,
                        const __bf16* __restrict__ VT, const float* __restrict__ REL,
                        const __bf16* __restrict__ SUFn, const __bf16* __restrict__ PREn,
                        const float* __restrict__ MT, const int* __restrict__ MFLAG,
                        __bf16* __restrict__ Ob) {
  const int bid = blockIdx.x;
  const int bh = (bid & 7) * 4 + ((bid >> 3) & 3);
  const int qt = bid >> 5;
  const int b = bh >> 3;
  const int tid = threadIdx.x, wid = tid >> 6, lane = tid & 63;
  const int l16 = lane & 15, lhi = lane >> 4;

  __shared__ __align__(16) __bf16 vbuf[2][32 * 128];   // 16 KB
  __shared__ __align__(16) __bf16 plds[8][16 * 64];    // 16 KB (2-phase reuse)

  const int qrow = qt * 128 + wid * 16 + l16;
  const size_t rg = (size_t)bh * SEQ + qrow;
  const bf16x8 qfrag = *(const bf16x8*)(Qb + rg * HD + lhi * 8);
  const float2 uw = *(const float2*)(REL + rg * 2);
  const float uu = uw.x, ww = uw.y, duw = uu - ww;
  const int flag = MFLAG[0];

  // static C0: c0[jt][r] = (jt*16 + lhi*4 + r) * duw (tile shift folded into max)
  f32x4 c0[8];
  {
    const f32x4 cr = {(float)(lhi * 4) * duw, (float)(lhi * 4 + 1) * duw,
                      (float)(lhi * 4 + 2) * duw, (float)(lhi * 4 + 3) * duw};
#pragma unroll
    for (int jt = 0; jt < 8; ++jt)
      c0[jt] = cr + (float)(jt * 16) * duw;
  }

  // K: per-lane global base (row l16, d-offset lhi*8) — coalesced 1KB per wave frag
  const __bf16* Kp = Kb + ((size_t)bh * SEQ + l16) * HD + lhi * 8;
  const int vd = tid >> 4, vc = tid & 15;
  const __bf16* vsrc = VT + ((size_t)bh * HD + vd) * SEQ + ((vc ^ (vd & 7)) * 8);

  f32x4 of0 = {0.f, 0.f, 0.f, 0.f}, of1 = {0.f, 0.f, 0.f, 0.f}, of2 = {0.f, 0.f, 0.f, 0.f};
  bf16x8 ones;
#pragma unroll
  for (int e = 0; e < 8; ++e) ones[e] = (__bf16)1.0f;
  float m = -3.0e38f;
  __bf16* pl = &plds[wid][0];
  const float* mtp = MT + b * SEQ + lhi * 4;

  // prologue: stage V tile 0, prefetch K fragments for tile 0 into registers
  GLOAD(vsrc, &vbuf[0][(size_t)tid * 8]);
  bf16x8 kf[8];
#pragma unroll
  for (int jt = 0; jt < 8; ++jt)
    kf[jt] = *(const bf16x8*)(Kp + (size_t)(jt * 16) * HD);
  __syncthreads();

  for (int t = 0, cur = 0; t < 16; ++t, cur ^= 1) {
    const int jb = t * 128;
    if (t < 15)
      GLOAD(vsrc + (jb + 128), &vbuf[cur ^ 1][(size_t)tid * 8]);
    const __bf16* vb = vbuf[cur];

    // QK^T swapped (K fragments already in registers)
    f32x4 sf[8];
    __builtin_amdgcn_s_setprio(1);
#pragma unroll
    for (int jt = 0; jt < 8; ++jt)
      sf[jt] = __builtin_amdgcn_mfma_f32_16x16x32_bf16(kf[jt], qfrag, c0[jt], 0, 0, 0);
    __builtin_amdgcn_s_setprio(0);

    // issue next tile's K loads immediately (latency hides under softmax+PV)
    if (t < 15) {
#pragma unroll
      for (int jt = 0; jt < 8; ++jt)
        kf[jt] = *(const bf16x8*)(Kp + (size_t)(jb + 128 + jt * 16) * HD);
    }

    if (t == 0) {
      const bf16x8 s0 = *(const bf16x8*)(SUFn + l16 * HD + lhi * 8);
      const bf16x8 s1 = *(const bf16x8*)(SUFn + (16 + l16) * HD + lhi * 8);
      sf[0] = __builtin_amdgcn_mfma_f32_16x16x32_bf16(s0, qfrag, sf[0], 0, 0, 0);
      sf[1] = __builtin_amdgcn_mfma_f32_16x16x32_bf16(s1, qfrag, sf[1], 0, 0, 0);
#pragma unroll
      for (int jt = 0; jt < 2; ++jt)
#pragma unroll
        for (int r = 0; r < 4; ++r)
          sf[jt][r] += fmaxf(31.f - (float)(jt * 16 + lhi * 4 + r), 0.f) * uu;
    }
    if (t == 15) {
      const bf16x8 p0 = *(const bf16x8*)(PREn + l16 * HD + lhi * 8);
      const bf16x8 p1 = *(const bf16x8*)(PREn + (16 + l16) * HD + lhi * 8);
      sf[6] = __builtin_amdgcn_mfma_f32_16x16x32_bf16(p0, qfrag, sf[6], 0, 0, 0);
      sf[7] = __builtin_amdgcn_mfma_f32_16x16x32_bf16(p1, qfrag, sf[7], 0, 0, 0);
#pragma unroll
      for (int jt = 6; jt < 8; ++jt)
#pragma unroll
        for (int r = 0; r < 4; ++r)
          sf[jt][r] += fmaxf((float)(jb + jt * 16 + lhi * 4 + r) - 2016.f, 0.f) * ww;
    }
    if (!flag) {
#pragma unroll
      for (int jt = 0; jt < 8; ++jt)
        sf[jt] += *(const f32x4*)(mtp + jb + jt * 16);
    }

    const float tsp = (float)jb * duw;
    float tmax = -3.0e38f;
#pragma unroll
    for (int jt = 0; jt < 8; ++jt)
      tmax = fmaxf(fmaxf(fmaxf(fmaxf(tmax, sf[jt].x), sf[jt].y), sf[jt].z), sf[jt].w);
    tmax = fmaxf(tmax, __shfl_xor(tmax, 16));
    tmax = fmaxf(tmax, __shfl_xor(tmax, 32));
    const float mn = fmaxf(m, tmax + tsp);
    const float c = __builtin_amdgcn_exp2f(m - mn);
    m = mn;
    const float m2 = mn - tsp;
    of0 *= c; of1 *= c; of2 *= c;

#pragma unroll
    for (int ph = 0; ph < 2; ++ph) {
#pragma unroll
      for (int jt = ph * 4; jt < ph * 4 + 4; ++jt) {
        union { __bf16 h4[4]; uint2 u; } pk;
#pragma unroll
        for (int r = 0; r < 4; ++r)
          pk.h4[r] = (__bf16)__builtin_amdgcn_exp2f(sf[jt][r] - m2);
        const int blk16 = (((jt & 3) * 2 + (lhi >> 1)) ^ (l16 & 7));
        *(uint2*)(pl + l16 * 64 + blk16 * 8 + (lhi & 1) * 4) = pk.u;
      }
      __builtin_amdgcn_s_setprio(1);
#pragma unroll
      for (int kt = ph * 2; kt < ph * 2 + 2; ++kt) {
        const int pblk = (((kt & 1) * 4 + lhi) ^ (l16 & 7));
        bf16x8 pf = *(const bf16x8*)(pl + l16 * 64 + pblk * 8);
        bf16x8 v0 = *(const bf16x8*)(vb + l16 * 128 + (((kt * 4 + lhi) ^ (l16 & 7)) * 8));
        bf16x8 v1 = *(const bf16x8*)(vb + (16 + l16) * 128 + (((kt * 4 + lhi) ^ (l16 & 7)) * 8));
        of0 = __builtin_amdgcn_mfma_f32_16x16x32_bf16(v0, pf, of0, 0, 0, 0);
        of1 = __builtin_amdgcn_mfma_f32_16x16x32_bf16(v1, pf, of1, 0, 0, 0);
        of2 = __builtin_amdgcn_mfma_f32_16x16x32_bf16(ones, pf, of2, 0, 0, 0);
      }
      __builtin_amdgcn_s_setprio(0);
    }
    __syncthreads();
  }

  const float inv = 1.0f / of2[0];
  union { __bf16 h4[4]; uint2 u; } o0, o1;
#pragma unroll
  for (int r = 0; r < 4; ++r) {
    o0.h4[r] = (__bf16)(of0[r] * inv);
    o1.h4[r] = (__bf16)(of1[r] * inv);
  }
  *(uint2*)(Ob + rg * HD + lhi * 4) = o0.u;
  *(uint2*)(Ob + rg * HD + 16 + lhi * 4) = o1.u;
}

// ============ launch ============
extern "C" void kernel_launch(void* const* d_in, const int* in_sizes, int n_in,
                              void* d_out, int out_size, void* d_ws, size_t ws_size,
                              hipStream_t stream) {
  (void)in_sizes; (void)n_in; (void)out_size; (void)ws_size;
  const float* query = (const float*)d_in[0];
  const float* mask  = (const float*)d_in[1];
  const float* Wq = (const float*)d_in[2];
  const float* bq = (const float*)d_in[3];
  const float* Wk = (const float*)d_in[4];
  const float* bk = (const float*)d_in[5];
  const float* Wv = (const float*)d_in[6];
  const float* bv = (const float*)d_in[7];
  const float* Wo = (const float*)d_in[8];
  const float* bo = (const float*)d_in[9];
  const float* tbl = (const float*)d_in[10];
  float* out = (float*)d_out;
  char* ws = (char*)d_ws;

  const size_t MB = 1024ull * 1024;
  __bf16* Xb    = (__bf16*)(ws);                          // 4 MB
  __bf16* Wt    = (__bf16*)(ws + 4 * MB);                 // 384 KB
  __bf16* WoT   = (__bf16*)(ws + 4 * MB + 393216);        // 128 KB
  __bf16* SUFn  = (__bf16*)(ws + 4 * MB + 524288);        // 2 KB
  __bf16* PREn  = (__bf16*)(ws + 4 * MB + 526336);        // 2 KB
  float*  WV2T  = (float*) (ws + 4 * MB + 528384);        // 16 KB
  float*  cbv   = (float*) (ws + 4 * MB + 544768);        // 64 B
  float*  MT    = (float*) (ws + 4 * MB + 544832);        // 32 KB
  int*    MFLAG = (int*)   (ws + 4 * MB + 577600);        // 4 B
  float*  REL   = (float*) (ws + 5 * MB);                 // 512 KB
  __bf16* Qb    = (__bf16*)(ws + 6 * MB);                 // 4 MB
  __bf16* Kb    = (__bf16*)(ws + 10 * MB);                // 4 MB
  __bf16* VT    = (__bf16*)(ws + 14 * MB);                // 4 MB
  __bf16* Ob    = (__bf16*)(ws + 18 * MB);                // 4 MB

  k_prep<<<83, 256, 0, stream>>>(mask, Wq, Wk, Wv, Wo, bq, tbl,
                                 Wt, WoT, MT, SUFn, PREn, WV2T, cbv, MFLAG);
  k_rel<<<256, 256, 0, stream>>>(query, WV2T, cbv, REL, Xb);
  k_gemm<0><<<dim3(64, 6), 256, 0, stream>>>(Xb, Wt, bq, bk, bv, Qb, Kb, VT, nullptr);
  k_flash<<<512, 512, 0, stream>>>(Qb, Kb, VT, REL, SUFn, PREn, MT, MFLAG, Ob);
  k_gemm<1><<<dim3(64, 4), 256, 0, stream>>>(Ob, WoT, bo, nullptr, nullptr,
                                             nullptr, nullptr, nullptr, out);
}

// Round 12
// 88.656 us; speedup vs baseline: 1.4586x; 1.4586x over previous
//
#include <hip/hip_runtime.h>
#include <hip/hip_bf16.h>
#include <math.h>

#define NH 8
#define HD 32
#define SEQ 2048
#define DM 256
#define SCALE 0.17677669529663687f      // 1/sqrt(32)
#define INV_SCALE 5.656854249492381f    // sqrt(32)
#define LOG2E 1.4426950408889634f
#define QSC (SCALE * LOG2E)
#define MNEG (-1e9f * LOG2E)

typedef float f32x4 __attribute__((ext_vector_type(4)));
typedef __bf16 bf16x8 __attribute__((ext_vector_type(8)));

#define GLOAD(g, l) __builtin_amdgcn_global_load_lds( \
    (const __attribute__((address_space(1))) void*)(g), \
    (__attribute__((address_space(3))) void*)(l), 16, 0, 0)

// ============ prep: X->bf16, LDS-tiled W transposes, MT+flag, SUFn/PREn, WV2T, cb ============
__global__ void k_prep(const float* __restrict__ query, const float* __restrict__ mask,
                       const float* __restrict__ Wq, const float* __restrict__ Wk,
                       const float* __restrict__ Wv, const float* __restrict__ Wo,
                       const float* __restrict__ bq, const float* __restrict__ tbl,
                       __bf16* __restrict__ Xb, __bf16* __restrict__ Wt,
                       __bf16* __restrict__ WoT, float* __restrict__ MT,
                       __bf16* __restrict__ SUFn, __bf16* __restrict__ PREn,
                       float* __restrict__ WV2T, float* __restrict__ cb,
                       int* __restrict__ MFLAG) {
  const int blk = blockIdx.x, tid = threadIdx.x;
  __shared__ float ts[64][65];
  __shared__ int okl;
  if (blk < 1024) {                      // X f32 -> bf16
    size_t i = (size_t)blk * 2048 + (size_t)tid * 8;
    float4 a = *(const float4*)(query + i);
    float4 b4 = *(const float4*)(query + i + 4);
    union { __bf16 h[8]; bf16x8 v; } o;
    o.h[0] = (__bf16)a.x;  o.h[1] = (__bf16)a.y;
    o.h[2] = (__bf16)a.z;  o.h[3] = (__bf16)a.w;
    o.h[4] = (__bf16)b4.x; o.h[5] = (__bf16)b4.y;
    o.h[6] = (__bf16)b4.z; o.h[7] = (__bf16)b4.w;
    *(bf16x8*)(Xb + i) = o.v;
  } else if (blk < 1088) {               // LDS-tiled transposes (48 QKV + 16 Wo)
    const int idx = blk - 1024;
    const float* W;
    __bf16* dst;
    int tile;
    if (idx < 48) {
      int which = idx >> 4;
      W = which == 0 ? Wq : (which == 1 ? Wk : Wv);
      dst = Wt + which * 65536;
      tile = idx & 15;
    } else {
      W = Wo; dst = WoT; tile = idx - 48;
    }
    const int tr = (tile >> 2) * 64, tc = (tile & 3) * 64;
#pragma unroll
    for (int p = 0; p < 4; ++p) {
      int row = p * 16 + (tid >> 4);
      int col = (tid & 15) * 4;
      float4 v = *(const float4*)(W + (size_t)(tr + row) * 256 + tc + col);
      ts[row][col] = v.x; ts[row][col + 1] = v.y;
      ts[row][col + 2] = v.z; ts[row][col + 3] = v.w;
    }
    __syncthreads();
#pragma unroll
    for (int p = 0; p < 2; ++p) {
      int n = p * 32 + (tid >> 3);
      int kb = (tid & 7) * 8;
      union { __bf16 h[8]; bf16x8 v; } o;
#pragma unroll
      for (int e = 0; e < 8; ++e) o.h[e] = (__bf16)ts[kb + e][n];
      *(bf16x8*)(dst + (size_t)(tc + n) * 256 + tr + kb) = o.v;
    }
  } else if (blk == 1088) {              // MT (log2e-folded) + mask-ones flag
    if (tid == 0) okl = 1;
    __syncthreads();
    bool ok = true;
    for (int i = tid; i < 4 * SEQ; i += 256) {
      float mv = mask[i];
      MT[i] = (1.0f - mv) * MNEG;
      ok &= (mv == 1.0f);
    }
    if (!ok) atomicAnd(&okl, 0);
    __syncthreads();
    if (tid == 0) MFLAG[0] = okl;
  } else if (blk == 1089) {              // SUFn/PREn (negated prefix sums, /SCALE)
    for (int idx = tid; idx < 1024; idx += 256) {
      int j = idx >> 5, d = idx & 31;
      float s = 0.f;
      for (int u = j + 33; u <= 63; ++u) s += tbl[u * 32 + d];
      SUFn[idx] = (__bf16)(-s * INV_SCALE);
    }
    for (int idx = tid; idx < 1024; idx += 256) {
      int jj = idx >> 5, d = idx & 31;
      float s = 0.f;
      for (int u = 1; u <= jj; ++u) s += tbl[u * 32 + d];
      PREn[idx] = (__bf16)(-s * INV_SCALE);
    }
  } else if (blk < 1106) {               // WV2T[16][256] (x log2e)
    int tg = (blk - 1090) * 256 + tid;
    int hv = tg >> 8, k = tg & 255;
    const float* T = tbl + ((hv & 1) ? 0 : 64 * 32);
    const float* w = Wq + (size_t)k * 256 + (hv >> 1) * 32;
    float acc = 0.f;
#pragma unroll
    for (int d = 0; d < 32; ++d) acc = fmaf(w[d], T[d], acc);
    WV2T[hv * 256 + k] = acc * LOG2E;
  } else {                               // cb[16]
    if (tid < 16) {
      const float* T = tbl + ((tid & 1) ? 0 : 64 * 32);
      float a = 0.f;
#pragma unroll
      for (int d = 0; d < 32; ++d) a = fmaf(bq[(tid >> 1) * 32 + d], T[d], a);
      cb[tid] = a * LOG2E;
    }
  }
}

// ============ REL = (X @ WV2T^T + cb), LDS-staged (f32 exact) ============
__launch_bounds__(256)
__global__ void k_rel(const float* __restrict__ X, const float* __restrict__ WV2T,
                      const float* __restrict__ cb, float* __restrict__ REL) {
  __shared__ float Xs[32][260];
  __shared__ float Ws[16][260];
  const int tid = threadIdx.x;
  const size_t base = (size_t)blockIdx.x * 32 * 256;
#pragma unroll
  for (int p = 0; p < 8; ++p) {
    int idx = p * 1024 + tid * 4;
    float4 v = *(const float4*)(X + base + idx);
    *(float4*)&Xs[idx >> 8][idx & 255] = v;
  }
#pragma unroll
  for (int p = 0; p < 4; ++p) {
    int idx = p * 1024 + tid * 4;
    float4 v = *(const float4*)(WV2T + idx);
    *(float4*)&Ws[idx >> 8][idx & 255] = v;
  }
  __syncthreads();
  const int hv = tid & 15, rl = tid >> 4;
  float a0 = cb[hv], a1 = a0;
  const float* xs0 = &Xs[rl][0];
  const float* xs1 = &Xs[rl + 16][0];
  const float* wsp = &Ws[hv][0];
#pragma unroll 8
  for (int k = 0; k < 256; ++k) {
    float w = wsp[k];
    a0 = fmaf(xs0[k], w, a0);
    a1 = fmaf(xs1[k], w, a1);
  }
  const int row0 = blockIdx.x * 32 + rl;
  const int h = hv >> 1, v = hv & 1;
  const int b0i = row0 >> 11, s0 = row0 & 2047;
  REL[((size_t)(b0i * NH + h) * SEQ + s0) * 2 + v] = a0;
  const int r1 = row0 + 16;
  const int b1i = r1 >> 11, s1 = r1 & 2047;
  REL[((size_t)(b1i * NH + h) * SEQ + s1) * 2 + v] = a1;
}

// ============ bf16 MFMA GEMM (r5 config: MODE0 BN=128, MODE1 BM=128/BN=64) ============
template <int MODE>
__launch_bounds__(256)
__global__ void k_gemm(const __bf16* __restrict__ A, const __bf16* __restrict__ Bt,
                       const float* __restrict__ b0, const float* __restrict__ b1,
                       const float* __restrict__ b2,
                       __bf16* __restrict__ Qb, __bf16* __restrict__ Kb,
                       __bf16* __restrict__ VTout, float* __restrict__ Y) {
  constexpr int BN = (MODE == 0) ? 128 : 64;
  constexpr int NFJ = BN / 32;
  __shared__ __align__(16) __bf16 As[128 * 64];
  __shared__ __align__(16) __bf16 Bs[BN * 64];
  const int tid = threadIdx.x, lane = tid & 63, wid = tid >> 6;
  const int l16 = lane & 15, lhi = lane >> 4;
  const int wr = wid >> 1, wc = wid & 1;
  const int m0 = blockIdx.x * 128, n0 = blockIdx.y * BN;

  f32x4 acc[4][NFJ];
#pragma unroll
  for (int i = 0; i < 4; ++i)
#pragma unroll
    for (int j = 0; j < NFJ; ++j) acc[i][j] = (f32x4){0.f, 0.f, 0.f, 0.f};

  for (int k0 = 0; k0 < 256; k0 += 64) {
    __syncthreads();
#pragma unroll
    for (int cc = 0; cc < 4; ++cc) {
      int cl = tid + cc * 256;
      int row = cl >> 3, kc = cl & 7;
      int k = k0 + ((kc ^ (row & 7)) * 8);
      const __bf16* src;
      if constexpr (MODE == 0) {
        src = A + (size_t)(m0 + row) * 256 + k;
      } else {
        int r = m0 + row, bb = r >> 11, s = r & 2047, h = k >> 5, dh = k & 31;
        src = A + ((size_t)(bb * NH + h) * SEQ + s) * HD + dh;
      }
      GLOAD(src, (__bf16*)As + (size_t)cl * 8);
    }
#pragma unroll
    for (int cc = 0; cc < NFJ; ++cc) {
      int cl = tid + cc * 256;
      int row = cl >> 3, kc = cl & 7;
      int k = k0 + ((kc ^ (row & 7)) * 8);
      GLOAD(Bt + (size_t)(n0 + row) * 256 + k, (__bf16*)Bs + (size_t)cl * 8);
    }
    __syncthreads();
#pragma unroll
    for (int kk = 0; kk < 64; kk += 32) {
      bf16x8 af[4], bfr[NFJ];
#pragma unroll
      for (int fi = 0; fi < 4; ++fi) {
        int row = wr * 64 + fi * 16 + l16;
        af[fi] = *(const bf16x8*)(As + row * 64 + ((((kk >> 3) + lhi) ^ (row & 7)) * 8));
      }
#pragma unroll
      for (int fj = 0; fj < NFJ; ++fj) {
        int row = wc * (BN / 2) + fj * 16 + l16;
        bfr[fj] = *(const bf16x8*)(Bs + row * 64 + ((((kk >> 3) + lhi) ^ (row & 7)) * 8));
      }
#pragma unroll
      for (int fi = 0; fi < 4; ++fi)
#pragma unroll
        for (int fj = 0; fj < NFJ; ++fj)
          acc[fi][fj] = __builtin_amdgcn_mfma_f32_16x16x32_bf16(af[fi], bfr[fj], acc[fi][fj], 0, 0, 0);
    }
  }
#pragma unroll
  for (int fi = 0; fi < 4; ++fi) {
#pragma unroll
    for (int fj = 0; fj < NFJ; ++fj) {
      int mrow = m0 + wr * 64 + fi * 16 + lhi * 4;
      int ncol = n0 + wc * (BN / 2) + fj * 16 + l16;
      if constexpr (MODE == 0) {
        int which = ncol >> 8, nw = ncol & 255, h = nw >> 5, dh = nw & 31;
        int bb = mrow >> 11, s0 = mrow & 2047;
        if (which == 2) {
          union { __bf16 h4[4]; uint2 u; } o;
#pragma unroll
          for (int r = 0; r < 4; ++r) o.h4[r] = (__bf16)(acc[fi][fj][r] + b2[nw]);
          *(uint2*)(VTout + ((size_t)(bb * NH + h) * HD + dh) * SEQ + s0) = o.u;
        } else {
          const float* bias = which == 0 ? b0 : b1;
#pragma unroll
          for (int r = 0; r < 4; ++r) {
            float v = acc[fi][fj][r] + bias[nw];
            size_t oi = ((size_t)(bb * NH + h) * SEQ + (s0 + r)) * HD + dh;
            if (which == 0) Qb[oi] = (__bf16)(v * QSC);
            else Kb[oi] = (__bf16)v;
          }
        }
      } else {
#pragma unroll
        for (int r = 0; r < 4; ++r)
          Y[(size_t)(mrow + r) * 256 + ncol] = acc[fi][fj][r] + b0[ncol];
      }
    }
  }
}

// ============ flash (r7/r10 proven): 128-row tiles, static-C0 MFMA, XCD swizzle,
//              halved 2-phase P-LDS, ones-MFMA lsum ============
__launch_bounds__(512, 4)
__global__ void k_flash(const __bf16* __restrict__ Qb, const __bf16* __restrict__ Kb,
                        const __bf16* __restrict__ VT, const float* __restrict__ REL,
                        const __bf16* __restrict__ SUFn, const __bf16* __restrict__ PREn,
                        const float* __restrict__ MT, const int* __restrict__ MFLAG,
                        __bf16* __restrict__ Ob) {
  const int bid = blockIdx.x;
  const int bh = (bid & 7) * 4 + ((bid >> 3) & 3);
  const int qt = bid >> 5;
  const int b = bh >> 3;
  const int tid = threadIdx.x, wid = tid >> 6, lane = tid & 63;
  const int l16 = lane & 15, lhi = lane >> 4;

  __shared__ __align__(16) __bf16 kbuf[2][128 * 32];   // 16 KB
  __shared__ __align__(16) __bf16 vbuf[2][32 * 128];   // 16 KB
  __shared__ __align__(16) __bf16 plds[8][16 * 64];    // 16 KB (2-phase reuse)

  const int qrow = qt * 128 + wid * 16 + l16;
  const size_t rg = (size_t)bh * SEQ + qrow;
  const bf16x8 qfrag = *(const bf16x8*)(Qb + rg * HD + lhi * 8);
  const float2 uw = *(const float2*)(REL + rg * 2);
  const float uu = uw.x, ww = uw.y, duw = uu - ww;
  const int flag = MFLAG[0];

  // static C0: c0[jt][r] = (jt*16 + lhi*4 + r) * duw (tile shift folded into max)
  f32x4 c0[8];
  {
    const f32x4 cr = {(float)(lhi * 4) * duw, (float)(lhi * 4 + 1) * duw,
                      (float)(lhi * 4 + 2) * duw, (float)(lhi * 4 + 3) * duw};
#pragma unroll
    for (int jt = 0; jt < 8; ++jt)
      c0[jt] = cr + (float)(jt * 16) * duw;
  }

  const int kj = tid >> 2, kc = tid & 3;
  const __bf16* ksrc = Kb + ((size_t)bh * SEQ + kj) * HD + ((kc ^ ((kj >> 1) & 3)) * 8);
  const int vd = tid >> 4, vc = tid & 15;
  const __bf16* vsrc = VT + ((size_t)bh * HD + vd) * SEQ + ((vc ^ (vd & 7)) * 8);

  f32x4 of0 = {0.f, 0.f, 0.f, 0.f}, of1 = {0.f, 0.f, 0.f, 0.f}, of2 = {0.f, 0.f, 0.f, 0.f};
  bf16x8 ones;
#pragma unroll
  for (int e = 0; e < 8; ++e) ones[e] = (__bf16)1.0f;
  float m = -3.0e38f;
  __bf16* pl = &plds[wid][0];
  const float* mtp = MT + b * SEQ + lhi * 4;

  GLOAD(ksrc, &kbuf[0][(size_t)tid * 8]);
  GLOAD(vsrc, &vbuf[0][(size_t)tid * 8]);
  __syncthreads();

  for (int t = 0, cur = 0; t < 16; ++t, cur ^= 1) {
    const int jb = t * 128;
    if (t < 15) {
      GLOAD(ksrc + (size_t)(jb + 128) * HD, &kbuf[cur ^ 1][(size_t)tid * 8]);
      GLOAD(vsrc + (jb + 128), &vbuf[cur ^ 1][(size_t)tid * 8]);
    }
    const __bf16* kb = kbuf[cur];
    const __bf16* vb = vbuf[cur];

    f32x4 sf[8];
    __builtin_amdgcn_s_setprio(1);
#pragma unroll
    for (int jt = 0; jt < 8; ++jt) {
      const int row = jt * 16 + l16;
      bf16x8 kf = *(const bf16x8*)(kb + row * 32 + ((lhi ^ ((row >> 1) & 3)) * 8));
      sf[jt] = __builtin_amdgcn_mfma_f32_16x16x32_bf16(kf, qfrag, c0[jt], 0, 0, 0);
    }
    __builtin_amdgcn_s_setprio(0);

    if (t == 0) {
      const bf16x8 s0 = *(const bf16x8*)(SUFn + l16 * HD + lhi * 8);
      const bf16x8 s1 = *(const bf16x8*)(SUFn + (16 + l16) * HD + lhi * 8);
      sf[0] = __builtin_amdgcn_mfma_f32_16x16x32_bf16(s0, qfrag, sf[0], 0, 0, 0);
      sf[1] = __builtin_amdgcn_mfma_f32_16x16x32_bf16(s1, qfrag, sf[1], 0, 0, 0);
#pragma unroll
      for (int jt = 0; jt < 2; ++jt)
#pragma unroll
        for (int r = 0; r < 4; ++r)
          sf[jt][r] += fmaxf(31.f - (float)(jt * 16 + lhi * 4 + r), 0.f) * uu;
    }
    if (t == 15) {
      const bf16x8 p0 = *(const bf16x8*)(PREn + l16 * HD + lhi * 8);
      const bf16x8 p1 = *(const bf16x8*)(PREn + (16 + l16) * HD + lhi * 8);
      sf[6] = __builtin_amdgcn_mfma_f32_16x16x32_bf16(p0, qfrag, sf[6], 0, 0, 0);
      sf[7] = __builtin_amdgcn_mfma_f32_16x16x32_bf16(p1, qfrag, sf[7], 0, 0, 0);
#pragma unroll
      for (int jt = 6; jt < 8; ++jt)
#pragma unroll
        for (int r = 0; r < 4; ++r)
          sf[jt][r] += fmaxf((float)(jb + jt * 16 + lhi * 4 + r) - 2016.f, 0.f) * ww;
    }
    if (!flag) {
#pragma unroll
      for (int jt = 0; jt < 8; ++jt)
        sf[jt] += *(const f32x4*)(mtp + jb + jt * 16);
    }

    const float tsp = (float)jb * duw;
    float tmax = -3.0e38f;
#pragma unroll
    for (int jt = 0; jt < 8; ++jt)
      tmax = fmaxf(fmaxf(fmaxf(fmaxf(tmax, sf[jt].x), sf[jt].y), sf[jt].z), sf[jt].w);
    tmax = fmaxf(tmax, __shfl_xor(tmax, 16));
    tmax = fmaxf(tmax, __shfl_xor(tmax, 32));
    const float mn = fmaxf(m, tmax + tsp);
    const float c = __builtin_amdgcn_exp2f(m - mn);
    m = mn;
    const float m2 = mn - tsp;
    of0 *= c; of1 *= c; of2 *= c;

#pragma unroll
    for (int ph = 0; ph < 2; ++ph) {
#pragma unroll
      for (int jt = ph * 4; jt < ph * 4 + 4; ++jt) {
        union { __bf16 h4[4]; uint2 u; } pk;
#pragma unroll
        for (int r = 0; r < 4; ++r)
          pk.h4[r] = (__bf16)__builtin_amdgcn_exp2f(sf[jt][r] - m2);
        const int blk16 = (((jt & 3) * 2 + (lhi >> 1)) ^ (l16 & 7));
        *(uint2*)(pl + l16 * 64 + blk16 * 8 + (lhi & 1) * 4) = pk.u;
      }
      __builtin_amdgcn_s_setprio(1);
#pragma unroll
      for (int kt = ph * 2; kt < ph * 2 + 2; ++kt) {
        const int pblk = (((kt & 1) * 4 + lhi) ^ (l16 & 7));
        bf16x8 pf = *(const bf16x8*)(pl + l16 * 64 + pblk * 8);
        bf16x8 v0 = *(const bf16x8*)(vb + l16 * 128 + (((kt * 4 + lhi) ^ (l16 & 7)) * 8));
        bf16x8 v1 = *(const bf16x8*)(vb + (16 + l16) * 128 + (((kt * 4 + lhi) ^ (l16 & 7)) * 8));
        of0 = __builtin_amdgcn_mfma_f32_16x16x32_bf16(v0, pf, of0, 0, 0, 0);
        of1 = __builtin_amdgcn_mfma_f32_16x16x32_bf16(v1, pf, of1, 0, 0, 0);
        of2 = __builtin_amdgcn_mfma_f32_16x16x32_bf16(ones, pf, of2, 0, 0, 0);
      }
      __builtin_amdgcn_s_setprio(0);
    }
    __syncthreads();
  }

  const float inv = 1.0f / of2[0];
  union { __bf16 h4[4]; uint2 u; } o0, o1;
#pragma unroll
  for (int r = 0; r < 4; ++r) {
    o0.h4[r] = (__bf16)(of0[r] * inv);
    o1.h4[r] = (__bf16)(of1[r] * inv);
  }
  *(uint2*)(Ob + rg * HD + lhi * 4) = o0.u;
  *(uint2*)(Ob + rg * HD + 16 + lhi * 4) = o1.u;
}

// ============ launch ============
extern "C" void kernel_launch(void* const* d_in, const int* in_sizes, int n_in,
                              void* d_out, int out_size, void* d_ws, size_t ws_size,
                              hipStream_t stream) {
  (void)in_sizes; (void)n_in; (void)out_size; (void)ws_size;
  const float* query = (const float*)d_in[0];
  const float* mask  = (const float*)d_in[1];
  const float* Wq = (const float*)d_in[2];
  const float* bq = (const float*)d_in[3];
  const float* Wk = (const float*)d_in[4];
  const float* bk = (const float*)d_in[5];
  const float* Wv = (const float*)d_in[6];
  const float* bv = (const float*)d_in[7];
  const float* Wo = (const float*)d_in[8];
  const float* bo = (const float*)d_in[9];
  const float* tbl = (const float*)d_in[10];
  float* out = (float*)d_out;
  char* ws = (char*)d_ws;

  const size_t MB = 1024ull * 1024;
  __bf16* Xb    = (__bf16*)(ws);                          // 4 MB
  __bf16* Wt    = (__bf16*)(ws + 4 * MB);                 // 384 KB
  __bf16* WoT   = (__bf16*)(ws + 4 * MB + 393216);        // 128 KB
  __bf16* SUFn  = (__bf16*)(ws + 4 * MB + 524288);        // 2 KB
  __bf16* PREn  = (__bf16*)(ws + 4 * MB + 526336);        // 2 KB
  float*  WV2T  = (float*) (ws + 4 * MB + 528384);        // 16 KB
  float*  cbv   = (float*) (ws + 4 * MB + 544768);        // 64 B
  float*  MT    = (float*) (ws + 4 * MB + 544832);        // 32 KB
  int*    MFLAG = (int*)   (ws + 4 * MB + 577600);        // 4 B
  float*  REL   = (float*) (ws + 5 * MB);                 // 512 KB
  __bf16* Qb    = (__bf16*)(ws + 6 * MB);                 // 4 MB
  __bf16* Kb    = (__bf16*)(ws + 10 * MB);                // 4 MB
  __bf16* VT    = (__bf16*)(ws + 14 * MB);                // 4 MB
  __bf16* Ob    = (__bf16*)(ws + 18 * MB);                // 4 MB

  k_prep<<<1107, 256, 0, stream>>>(query, mask, Wq, Wk, Wv, Wo, bq, tbl,
                                   Xb, Wt, WoT, MT, SUFn, PREn, WV2T, cbv, MFLAG);
  k_rel<<<256, 256, 0, stream>>>(query, WV2T, cbv, REL);
  k_gemm<0><<<dim3(64, 6), 256, 0, stream>>>(Xb, Wt, bq, bk, bv, Qb, Kb, VT, nullptr);
  k_flash<<<512, 512, 0, stream>>>(Qb, Kb, VT, REL, SUFn, PREn, MT, MFLAG, Ob);
  k_gemm<1><<<dim3(64, 4), 256, 0, stream>>>(Ob, WoT, bo, nullptr, nullptr,
                                             nullptr, nullptr, nullptr, out);
}